// Round 9
// baseline (452.090 us; speedup 1.0000x reference)
//
#include <hip/hip_runtime.h>
#include <cstdint>
#include <cstddef>

#define DEV_INLINE __device__ __forceinline__

typedef __bf16 bf16;
typedef __bf16 bf16x4 __attribute__((ext_vector_type(4)));
typedef __bf16 bf16x8 __attribute__((ext_vector_type(8)));
typedef float f32x4 __attribute__((ext_vector_type(4)));

// Problem constants
static constexpr int Bb = 8;
static constexpr int Nn = 1024;
static constexpr int Cc = 768;
static constexpr int HD = 96;   // head dim
static constexpr int GD = 384;  // group dim
#define SCALE_ 0.1020620726159658f  // 96^-0.5 (reference uses hd^-0.5 for BOTH attentions)

// ---------------------------------------------------------------------------
// async global->LDS, 16B per lane. LDS dest must be wave-uniform base; HW does
// base + lane*16.
DEV_INLINE void gload_lds16(void* lds, const void* g) {
  __builtin_amdgcn_global_load_lds(
      (__attribute__((address_space(1))) void*)(void*)g,
      (__attribute__((address_space(3))) void*)lds, 16, 0, 0);
}

// ---------------------------------------------------------------------------
// Fused f32 -> bf16 cast of x + all 4 weight matrices, 8 elems/thread.
// Segment boundaries (flat elems): x 6291456 | w_qkv 1769472 | w_g0 442368 |
// w_g1 442368 | w_proj 589824; total 9535488 = 4656 blocks * 256 thr * 8.
__global__ void k_convert_all(const float* __restrict__ x, const float* __restrict__ wqkv,
                              const float* __restrict__ wg0, const float* __restrict__ wg1,
                              const float* __restrict__ wproj,
                              bf16* __restrict__ xb, bf16* __restrict__ wqkvb,
                              bf16* __restrict__ wg0b, bf16* __restrict__ wg1b,
                              bf16* __restrict__ wprojb) {
  const int i = (blockIdx.x * 256 + threadIdx.x) * 8;
  const float* src; bf16* dst; int off;
  if (i < 6291456)      { src = x;     dst = xb;     off = i; }
  else if (i < 8060928) { src = wqkv;  dst = wqkvb;  off = i - 6291456; }
  else if (i < 8503296) { src = wg0;   dst = wg0b;   off = i - 8060928; }
  else if (i < 8945664) { src = wg1;   dst = wg1b;   off = i - 8503296; }
  else                  { src = wproj; dst = wprojb; off = i - 8945664; }
  float4 a = *(const float4*)(src + off);
  float4 b = *(const float4*)(src + off + 4);
  bf16x8 o;
  o[0] = (bf16)a.x; o[1] = (bf16)a.y; o[2] = (bf16)a.z; o[3] = (bf16)a.w;
  o[4] = (bf16)b.x; o[5] = (bf16)b.y; o[6] = (bf16)b.z; o[7] = (bf16)b.w;
  *(bf16x8*)(dst + off) = o;
}

// ---------------------------------------------------------------------------
// cur = x[:, gi*384 : gi*384+384] (+ hx if gi==1), cast bf16. 8 elems/thread.
__global__ void k_make_cur(const float* __restrict__ x, const float* __restrict__ hx,
                           bf16* __restrict__ cur, int gi) {
  int t = blockIdx.x * 256 + threadIdx.x;      // 8192*384/8 threads
  int m = t / 48;
  int d0 = (t % 48) * 8;
  const float* xr = x + (size_t)m * Cc + gi * GD + d0;
  float4 a = *(const float4*)xr;
  float4 b = *(const float4*)(xr + 4);
  if (gi) {
    const float* hr = hx + (size_t)m * GD + d0;
    float4 c = *(const float4*)hr;
    float4 d = *(const float4*)(hr + 4);
    a.x += c.x; a.y += c.y; a.z += c.z; a.w += c.w;
    b.x += d.x; b.y += d.y; b.z += d.z; b.w += d.w;
  }
  bf16x8 o;
  o[0] = (bf16)a.x; o[1] = (bf16)a.y; o[2] = (bf16)a.z; o[3] = (bf16)a.w;
  o[4] = (bf16)b.x; o[5] = (bf16)b.y; o[6] = (bf16)b.z; o[7] = (bf16)b.w;
  *(bf16x8*)(cur + (size_t)m * GD + d0) = o;
}

// ---------------------------------------------------------------------------
// Generic C = A @ W^T GEMM. A: [M][K] bf16, W: [Ncols][K] bf16.
// 128x128 tile, BK=32, 256 thr (4 waves, 2x2 wave grid, 64x64 per wave),
// mfma_f32_16x16x32_bf16, global_load_lds staging.
// blockIdx.z: batch (A += z*aZ, W += z*wZ) for EPI 3/4; gridDim.z==1 otherwise.
// Frag conventions (verified layouts):
//   A/B frag: lane l holds Mat[t0 + (l&15)][k0 + (l>>4)*8 + i], i=0..7
//   C/D:      lane l reg r -> row = m0 + (l>>4)*4 + r, col = n0 + (l&15)
// EPI 0: qkv scatter -> o0=Q(b,h,n,d) o1=K(b,h,n,d) o2=Vt(b,h,d,n), all bf16
// EPI 1: grp scatter -> o0=q2(m,d) o1=k2(m,d) o2=v2t(b,d,n), bf16
// EPI 2: f0[row*768+col] = val + bias[col], fp32
// EPI 3: o0[(z*1024+row)*1024+col] = bf16(val*SCALE_)          (S logits)
// EPI 4: f0=hx[(z*1024+row)*384+col]=val;
//        o1=cat[(z*1024+row)*768+gi*384+col]=bf16(val+origin[same idx])
template <int EPI>
__global__ __launch_bounds__(256, 2)
void k_gemm(const bf16* __restrict__ A, const bf16* __restrict__ W, int K,
            int aZ, int wZ,
            bf16* __restrict__ o0, bf16* __restrict__ o1, bf16* __restrict__ o2,
            float* __restrict__ f0, const float* __restrict__ bias,
            const float* __restrict__ origin, int gi) {
  const int bm = blockIdx.x, bn = blockIdx.y, bz = blockIdx.z;
  const int tid = threadIdx.x;
  const int wave = tid >> 6, lane = tid & 63;
  const int wr = wave >> 1, wc = wave & 1;
  const int l15 = lane & 15, l4 = lane >> 4;

  A += (size_t)bz * aZ;
  W += (size_t)bz * wZ;

  __shared__ bf16 As[128 * 32];
  __shared__ bf16 Bs[128 * 32];

  f32x4 acc[4][4] = {};

  // staging geometry: flat elem e = thread*8 (issue0) / +2048 (issue1)
  const int t8 = tid * 8;
  const int r0 = t8 >> 5, c0 = t8 & 31;
  const int r1 = r0 + 64;
  const bf16* Arow0 = A + (size_t)(bm * 128 + r0) * K + c0;
  const bf16* Arow1 = A + (size_t)(bm * 128 + r1) * K + c0;
  const bf16* Brow0 = W + (size_t)(bn * 128 + r0) * K + c0;
  const bf16* Brow1 = W + (size_t)(bn * 128 + r1) * K + c0;
  bf16* sA0 = &As[wave * 512];
  bf16* sA1 = &As[2048 + wave * 512];
  bf16* sB0 = &Bs[wave * 512];
  bf16* sB1 = &Bs[2048 + wave * 512];

  for (int k0 = 0; k0 < K; k0 += 32) {
    gload_lds16(sA0, Arow0 + k0);
    gload_lds16(sA1, Arow1 + k0);
    gload_lds16(sB0, Brow0 + k0);
    gload_lds16(sB1, Brow1 + k0);
    __syncthreads();
    bf16x8 af[4], bfr[4];
#pragma unroll
    for (int i = 0; i < 4; ++i) {
      af[i]  = *(const bf16x8*)&As[(wr * 64 + i * 16 + l15) * 32 + l4 * 8];
      bfr[i] = *(const bf16x8*)&Bs[(wc * 64 + i * 16 + l15) * 32 + l4 * 8];
    }
#pragma unroll
    for (int i = 0; i < 4; ++i)
#pragma unroll
      for (int j = 0; j < 4; ++j)
        acc[i][j] = __builtin_amdgcn_mfma_f32_16x16x32_bf16(af[i], bfr[j], acc[i][j], 0, 0, 0);
    __syncthreads();
  }

#pragma unroll
  for (int i = 0; i < 4; ++i) {
    const int mbase = bm * 128 + wr * 64 + i * 16 + l4 * 4;
#pragma unroll
    for (int j = 0; j < 4; ++j) {
      const int col = bn * 128 + wc * 64 + j * 16 + l15;
#pragma unroll
      for (int r = 0; r < 4; ++r) {
        const int row = mbase + r;
        const float val = acc[i][j][r];
        if constexpr (EPI == 2) {
          f0[(size_t)row * 768 + col] = val + bias[col];
        } else if constexpr (EPI == 3) {
          o0[((size_t)bz * 1024 + row) * 1024 + col] = (bf16)(val * SCALE_);
        } else if constexpr (EPI == 4) {
          const size_t gr = (size_t)bz * 1024 + row;
          f0[gr * 384 + col] = val;
          const size_t ci = gr * 768 + gi * 384 + col;
          o1[ci] = (bf16)(val + origin[ci]);
        } else if constexpr (EPI == 0) {
          const int bb = row >> 10, n = row & 1023;
          const int sct = col / 768, rem = col % 768;
          const int hh = rem / 96, dd = rem % 96;
          const bf16 bv = (bf16)val;
          if (sct == 0)      o0[((size_t)(bb * 8 + hh) * 1024 + n) * 96 + dd] = bv;
          else if (sct == 1) o1[((size_t)(bb * 8 + hh) * 1024 + n) * 96 + dd] = bv;
          else               o2[((size_t)(bb * 8 + hh) * 96 + dd) * 1024 + n] = bv;
        } else {
          const int bb = row >> 10, n = row & 1023;
          const int sct = col / 384, dd = col % 384;
          const bf16 bv = (bf16)val;
          if (sct == 0)      o0[(size_t)row * 384 + dd] = bv;
          else if (sct == 1) o1[(size_t)row * 384 + dd] = bv;
          else               o2[((size_t)bb * 384 + dd) * 1024 + n] = bv;
        }
      }
    }
  }
}

// ---------------------------------------------------------------------------
// In-place row softmax on bf16 logits. One wave per row of 1024.
// Grid: rows/4 blocks x 256 threads (4 waves). Barrier-free.
__global__ __launch_bounds__(256)
void k_softmax_rows(bf16* __restrict__ SP) {
  const int row = blockIdx.x * 4 + (threadIdx.x >> 6);
  const int lane = threadIdx.x & 63;
  bf16* R = SP + (size_t)row * 1024 + lane * 16;
  bf16x8 a = *(const bf16x8*)R;
  bf16x8 b = *(const bf16x8*)(R + 8);
  float v[16];
#pragma unroll
  for (int i = 0; i < 8; ++i) { v[i] = (float)a[i]; v[8 + i] = (float)b[i]; }
  float mx = -1e30f;
#pragma unroll
  for (int i = 0; i < 16; ++i) mx = fmaxf(mx, v[i]);
  mx = fmaxf(mx, __shfl_xor(mx, 1));
  mx = fmaxf(mx, __shfl_xor(mx, 2));
  mx = fmaxf(mx, __shfl_xor(mx, 4));
  mx = fmaxf(mx, __shfl_xor(mx, 8));
  mx = fmaxf(mx, __shfl_xor(mx, 16));
  mx = fmaxf(mx, __shfl_xor(mx, 32));
  float s = 0.f;
#pragma unroll
  for (int i = 0; i < 16; ++i) { v[i] = __expf(v[i] - mx); s += v[i]; }
  s += __shfl_xor(s, 1);
  s += __shfl_xor(s, 2);
  s += __shfl_xor(s, 4);
  s += __shfl_xor(s, 8);
  s += __shfl_xor(s, 16);
  s += __shfl_xor(s, 32);
  const float inv = 1.f / s;
#pragma unroll
  for (int i = 0; i < 8; ++i) { a[i] = (bf16)(v[i] * inv); b[i] = (bf16)(v[8 + i] * inv); }
  *(bf16x8*)R = a;
  *(bf16x8*)(R + 8) = b;
}

// ---------------------------------------------------------------------------
// Flash MHA step (always-inline): software-pipelined.
//   - V frags for THIS step loaded first (hide under QK + softmax)
//   - K frags for NEXT step (kn) loaded right after QK consumes kc
//   - swapped QK^T: lane holds P[kv][q=l15]; lane-local softmax
DEV_INLINE void mha_step(const bf16* __restrict__ Kh, const bf16* __restrict__ Vh,
                         int n0, int npre,
                         const bf16x8 (&qf)[3], bf16x8 (&kc)[12], bf16x8 (&kn)[12],
                         f32x4 (&o)[6], float& mrow, float& lrow,
                         bf16* Pl, float* Ax, int l15, int l4) {
  // V loads for this step — independent of QK/softmax, issued first
  bf16x8 vf[12];
#pragma unroll
  for (int df = 0; df < 6; ++df)
#pragma unroll
    for (int kf2 = 0; kf2 < 2; ++kf2)
      vf[df * 2 + kf2] = *(const bf16x8*)&Vh[(size_t)(df * 16 + l15) * Nn + n0 + kf2 * 32 + l4 * 8];
  // QK with current K frags (SWAPPED: A=K, B=Q -> D[kv][q], lane's q = l15)
  f32x4 s[4] = {};
#pragma unroll
  for (int nf = 0; nf < 4; ++nf)
#pragma unroll
    for (int kf = 0; kf < 3; ++kf)
      s[nf] = __builtin_amdgcn_mfma_f32_16x16x32_bf16(kc[nf * 3 + kf], qf[kf], s[nf], 0, 0, 0);
  // prefetch next step's K frags (unconditional, clamped index)
#pragma unroll
  for (int nf = 0; nf < 4; ++nf)
#pragma unroll
    for (int kf = 0; kf < 3; ++kf)
      kn[nf * 3 + kf] = *(const bf16x8*)&Kh[(size_t)(npre + nf * 16 + l15) * HD + kf * 32 + l4 * 8];
  // lane-local softmax over the 16 P values (all for q = l15)
  float pmax = -1e30f;
#pragma unroll
  for (int nf = 0; nf < 4; ++nf)
#pragma unroll
    for (int r = 0; r < 4; ++r) {
      s[nf][r] *= SCALE_;
      pmax = fmaxf(pmax, s[nf][r]);
    }
  pmax = fmaxf(pmax, __shfl_xor(pmax, 16));
  pmax = fmaxf(pmax, __shfl_xor(pmax, 32));
  // defer-max: rescale only when some q's max grew by > 8
  if (__any(pmax > mrow + 8.f)) {
    const float mnew = fmaxf(mrow, pmax);
    const float alpha = __expf(mrow - mnew);
    mrow = mnew;
    lrow *= alpha;
    if (l4 == 0) Ax[l15] = alpha;            // broadcast alpha by q
    float ar[4];
#pragma unroll
    for (int r = 0; r < 4; ++r) ar[r] = Ax[l4 * 4 + r];
#pragma unroll
    for (int df = 0; df < 6; ++df)
#pragma unroll
      for (int r = 0; r < 4; ++r) o[df][r] *= ar[r];
  }
  float ls = 0.f;
#pragma unroll
  for (int nf = 0; nf < 4; ++nf)
#pragma unroll
    for (int r = 0; r < 4; ++r) {
      const float p = __expf(s[nf][r] - mrow);
      s[nf][r] = p;
      ls += p;
    }
  ls += __shfl_xor(ls, 16);
  ls += __shfl_xor(ls, 32);
  lrow += ls;
  // P -> LDS: P[q=l15][kv=nf*16+l4*4 .. +3], packed 8B writes
#pragma unroll
  for (int nf = 0; nf < 4; ++nf) {
    bf16x4 pk;
    pk[0] = (bf16)s[nf][0]; pk[1] = (bf16)s[nf][1];
    pk[2] = (bf16)s[nf][2]; pk[3] = (bf16)s[nf][3];
    *(bf16x4*)&Pl[l15 * 88 + nf * 16 + l4 * 4] = pk;
  }
  bf16x8 pa[2];
#pragma unroll
  for (int kf2 = 0; kf2 < 2; ++kf2)
    pa[kf2] = *(const bf16x8*)&Pl[l15 * 88 + kf2 * 32 + l4 * 8];
  // PV with the pre-loaded V frags
#pragma unroll
  for (int df = 0; df < 6; ++df)
#pragma unroll
    for (int kf2 = 0; kf2 < 2; ++kf2)
      o[df] = __builtin_amdgcn_mfma_f32_16x16x32_bf16(pa[kf2], vf[df * 2 + kf2], o[df], 0, 0, 0);
}

// Flash MHA, hd=96, swapped QK^T + SW pipeline (V-early, K double-buffer).
// Grid (64 bh, 16 qblk), 4 waves * 16 Q-rows. ~200 VGPR, 2 waves/SIMD —
// per-wave ILP replaces TLP (latency-bound regime, m97-GEMM tradeoff).
__global__ __launch_bounds__(256, 2)
void k_flash_mha(const bf16* __restrict__ Q, const bf16* __restrict__ Kt,
                 const bf16* __restrict__ Vt, float* __restrict__ origin) {
  const int bh = blockIdx.x, qb = blockIdx.y;
  const int b = bh >> 3, h = bh & 7;
  const int wave = threadIdx.x >> 6, lane = threadIdx.x & 63;
  const int l15 = lane & 15, l4 = lane >> 4;
  const bf16* Qh = Q + (size_t)bh * Nn * HD;
  const bf16* Kh = Kt + (size_t)bh * Nn * HD;
  const bf16* Vh = Vt + (size_t)bh * HD * Nn;
  const int q0 = qb * 64 + wave * 16;

  bf16x8 qf[3];
#pragma unroll
  for (int kf = 0; kf < 3; ++kf)
    qf[kf] = *(const bf16x8*)&Qh[(size_t)(q0 + l15) * HD + kf * 32 + l4 * 8];

  f32x4 o[6] = {};
  float mrow = -1e30f, lrow = 0.f;   // state for q = q0 + l15

  __shared__ bf16 Plds[4][16 * 88];  // per-wave P (stride 88: 16B-aligned rows)
  __shared__ float aux[4][16];       // per-wave alpha / l broadcast
  bf16* Pl = &Plds[wave][0];
  float* Ax = &aux[wave][0];

  // prologue: K frags for step 0
  bf16x8 ka[12], kb2[12];
#pragma unroll
  for (int nf = 0; nf < 4; ++nf)
#pragma unroll
    for (int kf = 0; kf < 3; ++kf)
      ka[nf * 3 + kf] = *(const bf16x8*)&Kh[(size_t)(nf * 16 + l15) * HD + kf * 32 + l4 * 8];

  for (int n0 = 0; n0 < Nn; n0 += 128) {
    mha_step(Kh, Vh, n0, n0 + 64, qf, ka, kb2, o, mrow, lrow, Pl, Ax, l15, l4);
    const int npre = (n0 + 128 < Nn) ? (n0 + 128) : (Nn - 64);
    mha_step(Kh, Vh, n0 + 64, npre, qf, kb2, ka, o, mrow, lrow, Pl, Ax, l15, l4);
  }

  // broadcast l by q, then normalize + write (o rows are q = q0 + l4*4 + r)
  if (l4 == 0) Ax[l15] = lrow;
  float linv[4];
#pragma unroll
  for (int r = 0; r < 4; ++r) linv[r] = 1.f / Ax[l4 * 4 + r];
  float* Og = origin + (size_t)b * Nn * Cc + h * HD;
#pragma unroll
  for (int r = 0; r < 4; ++r) {
    const int row = q0 + l4 * 4 + r;
#pragma unroll
    for (int df = 0; df < 6; ++df)
      Og[(size_t)row * Cc + df * 16 + l15] = o[df][r] * linv[r];
  }
}

// ---------------------------------------------------------------------------
extern "C" void kernel_launch(void* const* d_in, const int* in_sizes, int n_in,
                              void* d_out, int out_size, void* d_ws, size_t ws_size,
                              hipStream_t stream) {
  const float* x      = (const float*)d_in[0];
  const float* w_qkv  = (const float*)d_in[1];
  const float* w_g0   = (const float*)d_in[2];
  const float* w_g1   = (const float*)d_in[3];
  const float* w_proj = (const float*)d_in[4];
  const float* b_proj = (const float*)d_in[5];
  float* out = (float*)d_out;

  char* ws = (char*)d_ws;
  size_t off = 0;
  auto alloc = [&](size_t bytes) {
    char* p = ws + off;
    off += (bytes + 255) & ~(size_t)255;
    return p;
  };
  bf16* xb     = (bf16*)alloc((size_t)8192 * 768 * 2);
  bf16* wqkvb  = (bf16*)alloc((size_t)2304 * 768 * 2);
  bf16* wg0b   = (bf16*)alloc((size_t)1152 * 384 * 2);
  bf16* wg1b   = (bf16*)alloc((size_t)1152 * 384 * 2);
  bf16* wprojb = (bf16*)alloc((size_t)768 * 768 * 2);
  float* origin = (float*)alloc((size_t)8192 * 768 * 4);
  char* R = alloc((size_t)67108864);  // union region (MHA phase / group phase)
  // MHA phase
  bf16* Qb = (bf16*)R;                    // 12.6 MB
  bf16* Kb = (bf16*)(R + 12582912);       // 12.6 MB
  bf16* Vt = (bf16*)(R + 25165824);       // 12.6 MB (ends 37.7 MB)
  // group phase (temporally after MHA)
  bf16* curb = (bf16*)R;                  // 6.3 MB
  bf16* q2   = (bf16*)(R + 6291456);      // 6.3 MB
  bf16* k2   = (bf16*)(R + 12582912);     // 6.3 MB
  bf16* v2t  = (bf16*)(R + 18874368);     // 6.3 MB
  float* hx  = (float*)(R + 25165824);    // 12.6 MB (persists iter0->iter1)
  bf16* cat  = (bf16*)(R + 37748736);     // 12.6 MB (persists to proj)
  bf16* SP   = (bf16*)(R + 50331648);     // 16.8 MB (S logits -> P, in place)
  // total ws use ~111 MB

  k_convert_all<<<dim3(4656), 256, 0, stream>>>(x, w_qkv, w_g0, w_g1, w_proj,
                                                xb, wqkvb, wg0b, wg1b, wprojb);

  k_gemm<0><<<dim3(64, 18), 256, 0, stream>>>(xb, wqkvb, 768, 0, 0, Qb, Kb, Vt, nullptr, nullptr, nullptr, 0);
  k_flash_mha<<<dim3(64, 16), 256, 0, stream>>>(Qb, Kb, Vt, origin);

  for (int gi = 0; gi < 2; ++gi) {
    const bf16* wg = gi ? wg1b : wg0b;
    k_make_cur<<<dim3(1536), 256, 0, stream>>>(x, hx, curb, gi);
    k_gemm<1><<<dim3(64, 9), 256, 0, stream>>>(curb, wg, 384, 0, 0, q2, k2, v2t, nullptr, nullptr, nullptr, 0);
    // S = scale * q2 @ k2^T  (per batch)
    k_gemm<3><<<dim3(8, 8, 8), 256, 0, stream>>>(q2, k2, 384, 1024 * 384, 1024 * 384,
                                                 SP, nullptr, nullptr, nullptr, nullptr, nullptr, 0);
    // softmax rows in place (8192 rows)
    k_softmax_rows<<<dim3(2048), 256, 0, stream>>>(SP);
    // hx = P @ V2; cat slice = bf16(hx + origin slice)
    k_gemm<4><<<dim3(8, 3, 8), 256, 0, stream>>>(SP, v2t, 1024, 1024 * 1024, 384 * 1024,
                                                 nullptr, cat, nullptr, hx, nullptr, origin, gi);
  }

  k_gemm<2><<<dim3(64, 6), 256, 0, stream>>>(cat, wprojb, 768, 0, 0, nullptr, nullptr, nullptr, out, b_proj, nullptr, 0);
}

// Round 10
// 361.910 us; speedup vs baseline: 1.2492x; 1.2492x over previous
//
#include <hip/hip_runtime.h>
#include <cstdint>
#include <cstddef>

#define DEV_INLINE __device__ __forceinline__

typedef __bf16 bf16;
typedef __bf16 bf16x4 __attribute__((ext_vector_type(4)));
typedef __bf16 bf16x8 __attribute__((ext_vector_type(8)));
typedef float f32x4 __attribute__((ext_vector_type(4)));

// Problem constants
static constexpr int Bb = 8;
static constexpr int Nn = 1024;
static constexpr int Cc = 768;
static constexpr int HD = 96;   // head dim
static constexpr int GD = 384;  // group dim
#define SCALE_ 0.1020620726159658f  // 96^-0.5 (reference uses hd^-0.5 for BOTH attentions)

// ---------------------------------------------------------------------------
// async global->LDS, 16B per lane. LDS dest must be wave-uniform base; HW does
// base + lane*16. Global source IS per-lane (pre-swizzle source for swizzled
// LDS layouts; keep dest linear).
DEV_INLINE void gload_lds16(void* lds, const void* g) {
  __builtin_amdgcn_global_load_lds(
      (__attribute__((address_space(1))) void*)(void*)g,
      (__attribute__((address_space(3))) void*)lds, 16, 0, 0);
}

// ---------------------------------------------------------------------------
// Fused f32 -> bf16 cast of x + all 4 weight matrices, 8 elems/thread.
// Segment boundaries (flat elems): x 6291456 | w_qkv 1769472 | w_g0 442368 |
// w_g1 442368 | w_proj 589824; total 9535488 = 4656 blocks * 256 thr * 8.
__global__ void k_convert_all(const float* __restrict__ x, const float* __restrict__ wqkv,
                              const float* __restrict__ wg0, const float* __restrict__ wg1,
                              const float* __restrict__ wproj,
                              bf16* __restrict__ xb, bf16* __restrict__ wqkvb,
                              bf16* __restrict__ wg0b, bf16* __restrict__ wg1b,
                              bf16* __restrict__ wprojb) {
  const int i = (blockIdx.x * 256 + threadIdx.x) * 8;
  const float* src; bf16* dst; int off;
  if (i < 6291456)      { src = x;     dst = xb;     off = i; }
  else if (i < 8060928) { src = wqkv;  dst = wqkvb;  off = i - 6291456; }
  else if (i < 8503296) { src = wg0;   dst = wg0b;   off = i - 8060928; }
  else if (i < 8945664) { src = wg1;   dst = wg1b;   off = i - 8503296; }
  else                  { src = wproj; dst = wprojb; off = i - 8945664; }
  float4 a = *(const float4*)(src + off);
  float4 b = *(const float4*)(src + off + 4);
  bf16x8 o;
  o[0] = (bf16)a.x; o[1] = (bf16)a.y; o[2] = (bf16)a.z; o[3] = (bf16)a.w;
  o[4] = (bf16)b.x; o[5] = (bf16)b.y; o[6] = (bf16)b.z; o[7] = (bf16)b.w;
  *(bf16x8*)(dst + off) = o;
}

// ---------------------------------------------------------------------------
// cur = x[:, gi*384 : gi*384+384] (+ hx if gi==1), cast bf16. 8 elems/thread.
__global__ void k_make_cur(const float* __restrict__ x, const float* __restrict__ hx,
                           bf16* __restrict__ cur, int gi) {
  int t = blockIdx.x * 256 + threadIdx.x;      // 8192*384/8 threads
  int m = t / 48;
  int d0 = (t % 48) * 8;
  const float* xr = x + (size_t)m * Cc + gi * GD + d0;
  float4 a = *(const float4*)xr;
  float4 b = *(const float4*)(xr + 4);
  if (gi) {
    const float* hr = hx + (size_t)m * GD + d0;
    float4 c = *(const float4*)hr;
    float4 d = *(const float4*)(hr + 4);
    a.x += c.x; a.y += c.y; a.z += c.z; a.w += c.w;
    b.x += d.x; b.y += d.y; b.z += d.z; b.w += d.w;
  }
  bf16x8 o;
  o[0] = (bf16)a.x; o[1] = (bf16)a.y; o[2] = (bf16)a.z; o[3] = (bf16)a.w;
  o[4] = (bf16)b.x; o[5] = (bf16)b.y; o[6] = (bf16)b.z; o[7] = (bf16)b.w;
  *(bf16x8*)(cur + (size_t)m * GD + d0) = o;
}

// ---------------------------------------------------------------------------
// Generic C = A @ W^T GEMM. A: [M][K] bf16, W: [Ncols][K] bf16.
// 128x128 tile, BK=32, 256 thr (4 waves, 2x2 wave grid, 64x64 per wave),
// mfma_f32_16x16x32_bf16, global_load_lds staging.
// blockIdx.z: batch (A += z*aZ, W += z*wZ) for EPI 3/4; gridDim.z==1 otherwise.
// Frag conventions (verified layouts):
//   A/B frag: lane l holds Mat[t0 + (l&15)][k0 + (l>>4)*8 + i], i=0..7
//   C/D:      lane l reg r -> row = m0 + (l>>4)*4 + r, col = n0 + (l&15)
// EPI 0: qkv scatter -> o0=Q(b,h,n,d) o1=K(b,h,n,d) o2=Vt(b,h,d,n), all bf16
// EPI 1: grp scatter -> o0=q2(m,d) o1=k2(m,d) o2=v2t(b,d,n), bf16
// EPI 2: f0[row*768+col] = val + bias[col], fp32
// EPI 3: o0[(z*1024+row)*1024+col] = bf16(val*SCALE_)          (S logits)
// EPI 4: f0=hx[(z*1024+row)*384+col]=val;
//        o1=cat[(z*1024+row)*768+gi*384+col]=bf16(val+origin[same idx])
template <int EPI>
__global__ __launch_bounds__(256, 2)
void k_gemm(const bf16* __restrict__ A, const bf16* __restrict__ W, int K,
            int aZ, int wZ,
            bf16* __restrict__ o0, bf16* __restrict__ o1, bf16* __restrict__ o2,
            float* __restrict__ f0, const float* __restrict__ bias,
            const float* __restrict__ origin, int gi) {
  const int bm = blockIdx.x, bn = blockIdx.y, bz = blockIdx.z;
  const int tid = threadIdx.x;
  const int wave = tid >> 6, lane = tid & 63;
  const int wr = wave >> 1, wc = wave & 1;
  const int l15 = lane & 15, l4 = lane >> 4;

  A += (size_t)bz * aZ;
  W += (size_t)bz * wZ;

  __shared__ bf16 As[128 * 32];
  __shared__ bf16 Bs[128 * 32];

  f32x4 acc[4][4] = {};

  // staging geometry: flat elem e = thread*8 (issue0) / +2048 (issue1)
  const int t8 = tid * 8;
  const int r0 = t8 >> 5, c0 = t8 & 31;
  const int r1 = r0 + 64;
  const bf16* Arow0 = A + (size_t)(bm * 128 + r0) * K + c0;
  const bf16* Arow1 = A + (size_t)(bm * 128 + r1) * K + c0;
  const bf16* Brow0 = W + (size_t)(bn * 128 + r0) * K + c0;
  const bf16* Brow1 = W + (size_t)(bn * 128 + r1) * K + c0;
  bf16* sA0 = &As[wave * 512];
  bf16* sA1 = &As[2048 + wave * 512];
  bf16* sB0 = &Bs[wave * 512];
  bf16* sB1 = &Bs[2048 + wave * 512];

  for (int k0 = 0; k0 < K; k0 += 32) {
    gload_lds16(sA0, Arow0 + k0);
    gload_lds16(sA1, Arow1 + k0);
    gload_lds16(sB0, Brow0 + k0);
    gload_lds16(sB1, Brow1 + k0);
    __syncthreads();
    bf16x8 af[4], bfr[4];
#pragma unroll
    for (int i = 0; i < 4; ++i) {
      af[i]  = *(const bf16x8*)&As[(wr * 64 + i * 16 + l15) * 32 + l4 * 8];
      bfr[i] = *(const bf16x8*)&Bs[(wc * 64 + i * 16 + l15) * 32 + l4 * 8];
    }
#pragma unroll
    for (int i = 0; i < 4; ++i)
#pragma unroll
      for (int j = 0; j < 4; ++j)
        acc[i][j] = __builtin_amdgcn_mfma_f32_16x16x32_bf16(af[i], bfr[j], acc[i][j], 0, 0, 0);
    __syncthreads();
  }

#pragma unroll
  for (int i = 0; i < 4; ++i) {
    const int mbase = bm * 128 + wr * 64 + i * 16 + l4 * 4;
#pragma unroll
    for (int j = 0; j < 4; ++j) {
      const int col = bn * 128 + wc * 64 + j * 16 + l15;
#pragma unroll
      for (int r = 0; r < 4; ++r) {
        const int row = mbase + r;
        const float val = acc[i][j][r];
        if constexpr (EPI == 2) {
          f0[(size_t)row * 768 + col] = val + bias[col];
        } else if constexpr (EPI == 3) {
          o0[((size_t)bz * 1024 + row) * 1024 + col] = (bf16)(val * SCALE_);
        } else if constexpr (EPI == 4) {
          const size_t gr = (size_t)bz * 1024 + row;
          f0[gr * 384 + col] = val;
          const size_t ci = gr * 768 + gi * 384 + col;
          o1[ci] = (bf16)(val + origin[ci]);
        } else if constexpr (EPI == 0) {
          const int bb = row >> 10, n = row & 1023;
          const int sct = col / 768, rem = col % 768;
          const int hh = rem / 96, dd = rem % 96;
          const bf16 bv = (bf16)val;
          if (sct == 0)      o0[((size_t)(bb * 8 + hh) * 1024 + n) * 96 + dd] = bv;
          else if (sct == 1) o1[((size_t)(bb * 8 + hh) * 1024 + n) * 96 + dd] = bv;
          else               o2[((size_t)(bb * 8 + hh) * 96 + dd) * 1024 + n] = bv;
        } else {
          const int bb = row >> 10, n = row & 1023;
          const int sct = col / 384, dd = col % 384;
          const bf16 bv = (bf16)val;
          if (sct == 0)      o0[(size_t)row * 384 + dd] = bv;
          else if (sct == 1) o1[(size_t)row * 384 + dd] = bv;
          else               o2[((size_t)bb * 384 + dd) * 1024 + n] = bv;
        }
      }
    }
  }
}

// ---------------------------------------------------------------------------
// In-place row softmax on bf16 logits. One wave per row of 1024.
// Grid: rows/4 blocks x 256 threads (4 waves). Barrier-free.
__global__ __launch_bounds__(256)
void k_softmax_rows(bf16* __restrict__ SP) {
  const int row = blockIdx.x * 4 + (threadIdx.x >> 6);
  const int lane = threadIdx.x & 63;
  bf16* R = SP + (size_t)row * 1024 + lane * 16;
  bf16x8 a = *(const bf16x8*)R;
  bf16x8 b = *(const bf16x8*)(R + 8);
  float v[16];
#pragma unroll
  for (int i = 0; i < 8; ++i) { v[i] = (float)a[i]; v[8 + i] = (float)b[i]; }
  float mx = -1e30f;
#pragma unroll
  for (int i = 0; i < 16; ++i) mx = fmaxf(mx, v[i]);
  mx = fmaxf(mx, __shfl_xor(mx, 1));
  mx = fmaxf(mx, __shfl_xor(mx, 2));
  mx = fmaxf(mx, __shfl_xor(mx, 4));
  mx = fmaxf(mx, __shfl_xor(mx, 8));
  mx = fmaxf(mx, __shfl_xor(mx, 16));
  mx = fmaxf(mx, __shfl_xor(mx, 32));
  float s = 0.f;
#pragma unroll
  for (int i = 0; i < 16; ++i) { v[i] = __expf(v[i] - mx); s += v[i]; }
  s += __shfl_xor(s, 1);
  s += __shfl_xor(s, 2);
  s += __shfl_xor(s, 4);
  s += __shfl_xor(s, 8);
  s += __shfl_xor(s, 16);
  s += __shfl_xor(s, 32);
  const float inv = 1.f / s;
#pragma unroll
  for (int i = 0; i < 8; ++i) { a[i] = (bf16)(v[i] * inv); b[i] = (bf16)(v[8 + i] * inv); }
  *(bf16x8*)R = a;
  *(bf16x8*)(R + 8) = b;
}

// ---------------------------------------------------------------------------
// Flash MHA, hd=96 — BLOCK-STAGED form (R7-R9 per-wave streaming plateaued at
// ~140us: every wave re-read the whole per-head K/V from L2/HBM, latency on
// the critical path). Grid (64 bh, 8 qb) = 512 blocks (2/CU), 4 waves * 32
// Q-rows. Per KV-step (64 rows): K tile (contiguous 12KB) and V tile staged
// into LDS via global_load_lds, double-buffered; one __syncthreads per step
// (compiler drains vmcnt before s_barrier). V staged with source-side XOR
// swizzle byte^=(row&7)<<4 (linear LDS dest; same XOR on read) to break the
// 128B-row-stride 16-way bank conflict. Swapped QK^T lane-local softmax as
// verified in R8/R9.
__global__ __launch_bounds__(256, 2)
void k_flash_mha(const bf16* __restrict__ Q, const bf16* __restrict__ Kt,
                 const bf16* __restrict__ Vt, float* __restrict__ origin) {
  const int bh = blockIdx.x, qb = blockIdx.y;
  const int b = bh >> 3, h = bh & 7;
  const int wave = threadIdx.x >> 6, lane = threadIdx.x & 63;
  const int l15 = lane & 15, l4 = lane >> 4;
  const bf16* Qh = Q + (size_t)bh * Nn * HD;
  const bf16* Kh = Kt + (size_t)bh * Nn * HD;
  const bf16* Vh = Vt + (size_t)bh * HD * Nn;
  const int q0 = qb * 128 + wave * 32;

  __shared__ bf16 Ks[2][64 * 96];    // K tile, row-major [kv][d], 192B rows
  __shared__ bf16 Vs[2][96 * 64];    // V^T tile, [d][kv], 128B rows, XOR-swz
  __shared__ bf16 Plds[4][32 * 88];  // per-wave P (stride 88)
  __shared__ float aux[4][32];       // per-wave alpha / l broadcast
  bf16* Pl = &Plds[wave][0];
  float* Ax = &aux[wave][0];

  bf16x8 qf[2][3];
#pragma unroll
  for (int mf = 0; mf < 2; ++mf)
#pragma unroll
    for (int kf = 0; kf < 3; ++kf)
      qf[mf][kf] = *(const bf16x8*)&Qh[(size_t)(q0 + mf * 16 + l15) * HD + kf * 32 + l4 * 8];

  f32x4 o[2][6] = {};
  float mrow[2] = {-1e30f, -1e30f}, lrow[2] = {0.f, 0.f};

  // --- staging: 12 chunks of 1KB each per tile (3 issues x 4 waves) ---
  auto stageK = [&](int buf, int n0) {
#pragma unroll
    for (int i = 0; i < 3; ++i) {
      const int c = i * 4 + wave;                       // chunk 0..11
      gload_lds16(&Ks[buf][c * 512], Kh + (size_t)n0 * 96 + c * 512 + lane * 8);
    }
  };
  auto stageV = [&](int buf, int n0) {
#pragma unroll
    for (int i = 0; i < 3; ++i) {
      const int c = i * 4 + wave;
      const int L = (c * 64 + lane) * 16;               // dest byte offset
      const int row = L >> 7;                           // d index
      const int colb = (L & 127) ^ ((row & 7) << 4);    // source swizzle
      gload_lds16(&Vs[buf][c * 512], Vh + (size_t)row * Nn + n0 + (colb >> 1));
    }
  };

  auto compute = [&](int buf) {
    // QK^T swapped: A=K, B=Q -> D[kv][q]; lane's q = l15
    f32x4 s[2][4] = {};
#pragma unroll
    for (int nf = 0; nf < 4; ++nf) {
      bf16x8 kfr[3];
#pragma unroll
      for (int kf = 0; kf < 3; ++kf)
        kfr[kf] = *(const bf16x8*)&Ks[buf][(nf * 16 + l15) * 96 + kf * 32 + l4 * 8];
#pragma unroll
      for (int kf = 0; kf < 3; ++kf)
#pragma unroll
        for (int mf = 0; mf < 2; ++mf)
          s[mf][nf] = __builtin_amdgcn_mfma_f32_16x16x32_bf16(kfr[kf], qf[mf][kf], s[mf][nf], 0, 0, 0);
    }
    // lane-local softmax (16 values per mf, all for q = l15)
    float pmax[2];
#pragma unroll
    for (int mf = 0; mf < 2; ++mf) {
      float mx = -1e30f;
#pragma unroll
      for (int nf = 0; nf < 4; ++nf)
#pragma unroll
        for (int r = 0; r < 4; ++r) {
          s[mf][nf][r] *= SCALE_;
          mx = fmaxf(mx, s[mf][nf][r]);
        }
      mx = fmaxf(mx, __shfl_xor(mx, 16));
      mx = fmaxf(mx, __shfl_xor(mx, 32));
      pmax[mf] = mx;
    }
    // defer-max: rescale only when some q's max grew by > 8
    const bool need = (pmax[0] > mrow[0] + 8.f) || (pmax[1] > mrow[1] + 8.f);
    if (__any(need)) {
#pragma unroll
      for (int mf = 0; mf < 2; ++mf) {
        const float mnew = fmaxf(mrow[mf], pmax[mf]);
        const float alpha = __expf(mrow[mf] - mnew);
        mrow[mf] = mnew;
        lrow[mf] *= alpha;
        if (l4 == 0) Ax[mf * 16 + l15] = alpha;
      }
      float ar[2][4];
#pragma unroll
      for (int mf = 0; mf < 2; ++mf)
#pragma unroll
        for (int r = 0; r < 4; ++r) ar[mf][r] = Ax[mf * 16 + l4 * 4 + r];
#pragma unroll
      for (int mf = 0; mf < 2; ++mf)
#pragma unroll
        for (int df = 0; df < 6; ++df)
#pragma unroll
          for (int r = 0; r < 4; ++r) o[mf][df][r] *= ar[mf][r];
    }
#pragma unroll
    for (int mf = 0; mf < 2; ++mf) {
      float ls = 0.f;
#pragma unroll
      for (int nf = 0; nf < 4; ++nf)
#pragma unroll
        for (int r = 0; r < 4; ++r) {
          const float p = __expf(s[mf][nf][r] - mrow[mf]);
          s[mf][nf][r] = p;
          ls += p;
        }
      ls += __shfl_xor(ls, 16);
      ls += __shfl_xor(ls, 32);
      lrow[mf] += ls;
    }
    // P -> LDS (packed 8B), then pa frags
#pragma unroll
    for (int mf = 0; mf < 2; ++mf)
#pragma unroll
      for (int nf = 0; nf < 4; ++nf) {
        bf16x4 pk;
        pk[0] = (bf16)s[mf][nf][0]; pk[1] = (bf16)s[mf][nf][1];
        pk[2] = (bf16)s[mf][nf][2]; pk[3] = (bf16)s[mf][nf][3];
        *(bf16x4*)&Pl[(mf * 16 + l15) * 88 + nf * 16 + l4 * 4] = pk;
      }
    bf16x8 pa[2][2];
#pragma unroll
    for (int mf = 0; mf < 2; ++mf)
#pragma unroll
      for (int kf2 = 0; kf2 < 2; ++kf2)
        pa[mf][kf2] = *(const bf16x8*)&Pl[(mf * 16 + l15) * 88 + kf2 * 32 + l4 * 8];
    // PV from swizzled Vs
#pragma unroll
    for (int df = 0; df < 6; ++df) {
      bf16x8 vfr[2];
#pragma unroll
      for (int kf2 = 0; kf2 < 2; ++kf2) {
        const int row = df * 16 + l15;
        const int addr = row * 128 + ((kf2 * 64 + l4 * 16) ^ ((row & 7) << 4));
        vfr[kf2] = *(const bf16x8*)((const char*)&Vs[buf][0] + addr);
      }
#pragma unroll
      for (int kf2 = 0; kf2 < 2; ++kf2)
#pragma unroll
        for (int mf = 0; mf < 2; ++mf)
          o[mf][df] = __builtin_amdgcn_mfma_f32_16x16x32_bf16(pa[mf][kf2], vfr[kf2], o[mf][df], 0, 0, 0);
    }
  };

  // --- pipeline: stage0, barrier, then {stage next | compute cur | barrier} ---
  stageK(0, 0);
  stageV(0, 0);
  __syncthreads();
  int cur = 0;
  for (int t = 0; t < 16; ++t) {
    const int nn = (t < 15) ? (t + 1) * 64 : 15 * 64;   // clamp: uniform work
    stageK(cur ^ 1, nn);
    stageV(cur ^ 1, nn);
    compute(cur);
    __syncthreads();
    cur ^= 1;
  }

  // broadcast l by q, normalize + write (o rows are q = q0 + mf*16 + l4*4 + r)
  if (l4 == 0) {
    Ax[l15] = lrow[0];
    Ax[16 + l15] = lrow[1];
  }
  float linv[2][4];
#pragma unroll
  for (int mf = 0; mf < 2; ++mf)
#pragma unroll
    for (int r = 0; r < 4; ++r) linv[mf][r] = 1.f / Ax[mf * 16 + l4 * 4 + r];
  float* Og = origin + (size_t)b * Nn * Cc + h * HD;
#pragma unroll
  for (int mf = 0; mf < 2; ++mf)
#pragma unroll
    for (int r = 0; r < 4; ++r) {
      const int row = q0 + mf * 16 + l4 * 4 + r;
#pragma unroll
      for (int df = 0; df < 6; ++df)
        Og[(size_t)row * Cc + df * 16 + l15] = o[mf][df][r] * linv[mf][r];
    }
}

// ---------------------------------------------------------------------------
extern "C" void kernel_launch(void* const* d_in, const int* in_sizes, int n_in,
                              void* d_out, int out_size, void* d_ws, size_t ws_size,
                              hipStream_t stream) {
  const float* x      = (const float*)d_in[0];
  const float* w_qkv  = (const float*)d_in[1];
  const float* w_g0   = (const float*)d_in[2];
  const float* w_g1   = (const float*)d_in[3];
  const float* w_proj = (const float*)d_in[4];
  const float* b_proj = (const float*)d_in[5];
  float* out = (float*)d_out;

  char* ws = (char*)d_ws;
  size_t off = 0;
  auto alloc = [&](size_t bytes) {
    char* p = ws + off;
    off += (bytes + 255) & ~(size_t)255;
    return p;
  };
  bf16* xb     = (bf16*)alloc((size_t)8192 * 768 * 2);
  bf16* wqkvb  = (bf16*)alloc((size_t)2304 * 768 * 2);
  bf16* wg0b   = (bf16*)alloc((size_t)1152 * 384 * 2);
  bf16* wg1b   = (bf16*)alloc((size_t)1152 * 384 * 2);
  bf16* wprojb = (bf16*)alloc((size_t)768 * 768 * 2);
  float* origin = (float*)alloc((size_t)8192 * 768 * 4);
  char* R = alloc((size_t)67108864);  // union region (MHA phase / group phase)
  // MHA phase
  bf16* Qb = (bf16*)R;                    // 12.6 MB
  bf16* Kb = (bf16*)(R + 12582912);       // 12.6 MB
  bf16* Vt = (bf16*)(R + 25165824);       // 12.6 MB (ends 37.7 MB)
  // group phase (temporally after MHA)
  bf16* curb = (bf16*)R;                  // 6.3 MB
  bf16* q2   = (bf16*)(R + 6291456);      // 6.3 MB
  bf16* k2   = (bf16*)(R + 12582912);     // 6.3 MB
  bf16* v2t  = (bf16*)(R + 18874368);     // 6.3 MB
  float* hx  = (float*)(R + 25165824);    // 12.6 MB (persists iter0->iter1)
  bf16* cat  = (bf16*)(R + 37748736);     // 12.6 MB (persists to proj)
  bf16* SP   = (bf16*)(R + 50331648);     // 16.8 MB (S logits -> P, in place)
  // total ws use ~111 MB

  k_convert_all<<<dim3(4656), 256, 0, stream>>>(x, w_qkv, w_g0, w_g1, w_proj,
                                                xb, wqkvb, wg0b, wg1b, wprojb);

  k_gemm<0><<<dim3(64, 18), 256, 0, stream>>>(xb, wqkvb, 768, 0, 0, Qb, Kb, Vt, nullptr, nullptr, nullptr, 0);
  k_flash_mha<<<dim3(64, 8), 256, 0, stream>>>(Qb, Kb, Vt, origin);

  for (int gi = 0; gi < 2; ++gi) {
    const bf16* wg = gi ? wg1b : wg0b;
    k_make_cur<<<dim3(1536), 256, 0, stream>>>(x, hx, curb, gi);
    k_gemm<1><<<dim3(64, 9), 256, 0, stream>>>(curb, wg, 384, 0, 0, q2, k2, v2t, nullptr, nullptr, nullptr, 0);
    // S = scale * q2 @ k2^T  (per batch)
    k_gemm<3><<<dim3(8, 8, 8), 256, 0, stream>>>(q2, k2, 384, 1024 * 384, 1024 * 384,
                                                 SP, nullptr, nullptr, nullptr, nullptr, nullptr, 0);
    // softmax rows in place (8192 rows)
    k_softmax_rows<<<dim3(2048), 256, 0, stream>>>(SP);
    // hx = P @ V2; cat slice = bf16(hx + origin slice)
    k_gemm<4><<<dim3(8, 3, 8), 256, 0, stream>>>(SP, v2t, 1024, 1024 * 1024, 384 * 1024,
                                                 nullptr, cat, nullptr, hx, nullptr, origin, gi);
  }

  k_gemm<2><<<dim3(64, 6), 256, 0, stream>>>(cat, wprojb, 768, 0, 0, nullptr, nullptr, nullptr, out, b_proj, nullptr, 0);
}